// Round 12
// baseline (108.208 us; speedup 1.0000x reference)
//
#include <hip/hip_runtime.h>

#define NN 32
#define MAX_ITERS 10
#define TPB 256

typedef float vfloat4 __attribute__((ext_vector_type(4)));  // native vec for nt builtin

// DAG projection, graph compile-time constant (children u+1,u+2; parents u-1,u-2).
//
// Math (validated R10, bit-exact vs reference; absmax 0.0039):
//  T1: after iteration 1's backward pass q is non-increasing, so every later
//      forward prefix-min pass is the identity -> deleted.
//  T2: within a backward pass q'[u+1] >= q'[u+2], so max_child = q'[u+1].
//  Backward pass = in-place descending med3 chain:
//      q[u] = med3(p[u], q[u+1](new), q[u-1](old));  u=31: fminf(p,q[30]);
//      u=0: fmaxf(p, q[1]).
//
// R10 counters: VALUBusy 15% (~6us), HBM 2.5 TB/s (30%) -> neither pipe busy.
// Single variable vs R10: NONTEMPORAL STORES. 16B/lane partial-line writes
// through write-allocate L2 trigger read-for-ownership fetches and evict x
// from L3 (FETCH_SIZE 33MB despite x being L3-sized). nt stores bypass
// allocation: no RFO, x stays L3-resident, writes stream straight out.
__global__ __launch_bounds__(TPB) void dag_constraint_kernel(
    const float* __restrict__ x, float* __restrict__ out, int brows)
{
    const int row = blockIdx.x * blockDim.x + threadIdx.x;
    if (row >= brows) return;

    const float4* __restrict__ xr =
        reinterpret_cast<const float4*>(x) + (size_t)row * (NN / 4);

    float p[NN], q[NN];
    #pragma unroll
    for (int k = 0; k < NN / 4; ++k) {
        float4 v = xr[k];
        p[4*k+0] = v.x; p[4*k+1] = v.y; p[4*k+2] = v.z; p[4*k+3] = v.w;
    }

    // sigmoid via v_exp + v_rcp (1 ulp; error << 0.0198 threshold)
    #pragma unroll
    for (int i = 0; i < NN; ++i) {
        p[i] = __builtin_amdgcn_rcpf(1.0f + __expf(-p[i]));
        q[i] = p[i];
    }

    #pragma unroll
    for (int it = 0; it < MAX_ITERS; ++it) {
        if (it == 0) {
            // forward prefix-min (identity for it>=1 by T1)
            #pragma unroll
            for (int u = 0; u < NN - 1; ++u)
                q[u + 1] = fminf(q[u + 1], q[u]);
        }
        // backward: in-place descending med3 chain (T2)
        q[NN - 1] = fminf(p[NN - 1], q[NN - 2]);
        #pragma unroll
        for (int u = NN - 2; u >= 1; --u)
            q[u] = __builtin_amdgcn_fmed3f(p[u], q[u + 1], q[u - 1]);
        q[0] = fmaxf(p[0], q[1]);
    }

    vfloat4* __restrict__ outr =
        reinterpret_cast<vfloat4*>(out) + (size_t)row * (NN / 4);
    #pragma unroll
    for (int k = 0; k < NN / 4; ++k) {
        vfloat4 v = { q[4*k+0], q[4*k+1], q[4*k+2], q[4*k+3] };
        __builtin_nontemporal_store(v, &outr[k]);   // global_store_dwordx4 ... nt
    }
}

extern "C" void kernel_launch(void* const* d_in, const int* in_sizes, int n_in,
                              void* d_out, int out_size, void* d_ws, size_t ws_size,
                              hipStream_t stream)
{
    const float* x = (const float*)d_in[0];
    float* out = (float*)d_out;

    int total = in_sizes[0];      // B * N
    int brows = total / NN;       // B rows

    int blocks = (brows + TPB - 1) / TPB;   // 2048
    dag_constraint_kernel<<<blocks, TPB, 0, stream>>>(x, out, brows);
}